// Round 3
// baseline (11203.634 us; speedup 1.0000x reference)
//
#include <hip/hip_runtime.h>

typedef __attribute__((ext_vector_type(8))) _Float16 f16x8;
typedef __attribute__((ext_vector_type(4))) float f32x4;

#define B_SZ 64
#define T_SZ 512
#define I_SZ 512
#define H_SZ 1024
#define G4   4096
#define NBLK 256

// barrier layout in ws (uints): grp g at g*32 (128B apart), root at 256, gen at 288
#define BAR_ROOT 256
#define BAR_GEN  288

// ---------- prep: transpose + gate-interleave weights ----------
// src: [R][1024] fp32 (gate q's U or V). dst: [4096][R] f16, dst[4*n+q][r] = src[r][n]
__global__ void trans_kernel(const float* __restrict__ src, _Float16* __restrict__ dst,
                             int R, int q) {
  __shared__ float tile[64][65];
  const int n0 = blockIdx.x * 64;
  const int r0 = blockIdx.y * 64;
  const int x = threadIdx.x & 63, y = threadIdx.x >> 6;
  #pragma unroll
  for (int it = 0; it < 16; ++it) {
    int r = y * 16 + it;
    tile[r][x] = src[(size_t)(r0 + r) * H_SZ + n0 + x];
  }
  __syncthreads();
  #pragma unroll
  for (int it = 0; it < 16; ++it) {
    int rn = y * 16 + it;
    dst[(size_t)(4 * (n0 + rn) + q) * R + r0 + x] = (_Float16)tile[x][rn];
  }
}

// ---------- prep: interleave bias ----------
__global__ void bias_kernel(const float* __restrict__ b0, const float* __restrict__ b1,
                            const float* __restrict__ b2, const float* __restrict__ b3,
                            float* __restrict__ dst) {
  int g = blockIdx.x * blockDim.x + threadIdx.x;
  if (g >= G4) return;
  int q = g & 3, n = g >> 2;
  const float* s = (q == 0) ? b0 : (q == 1) ? b1 : (q == 2) ? b2 : b3;
  dst[g] = s[n];
}

// ---------- grid barrier: two-level generation barrier, AGENT scope ----------
__device__ __forceinline__ void gbar(unsigned* bar, int blk) {
  __syncthreads();
  if (threadIdx.x == 0) {
    const int g = blk >> 5;  // 8 groups x 32 blocks
    unsigned gen = __hip_atomic_load(bar + BAR_GEN, __ATOMIC_RELAXED, __HIP_MEMORY_SCOPE_AGENT);
    // release: publishes this block's h/out stores (wbL2 to LLC)
    unsigned a = __hip_atomic_fetch_add(bar + g * 32, 1u, __ATOMIC_RELEASE, __HIP_MEMORY_SCOPE_AGENT);
    if (a == 31u) {
      __hip_atomic_store(bar + g * 32, 0u, __ATOMIC_RELAXED, __HIP_MEMORY_SCOPE_AGENT);
      unsigned r = __hip_atomic_fetch_add(bar + BAR_ROOT, 1u, __ATOMIC_ACQ_REL, __HIP_MEMORY_SCOPE_AGENT);
      if (r == 7u) {
        __hip_atomic_store(bar + BAR_ROOT, 0u, __ATOMIC_RELAXED, __HIP_MEMORY_SCOPE_AGENT);
        __hip_atomic_store(bar + BAR_GEN, gen + 1u, __ATOMIC_RELEASE, __HIP_MEMORY_SCOPE_AGENT);
      } else {
        while (__hip_atomic_load(bar + BAR_GEN, __ATOMIC_RELAXED, __HIP_MEMORY_SCOPE_AGENT) == gen)
          __builtin_amdgcn_s_sleep(2);
      }
    } else {
      while (__hip_atomic_load(bar + BAR_GEN, __ATOMIC_RELAXED, __HIP_MEMORY_SCOPE_AGENT) == gen)
        __builtin_amdgcn_s_sleep(2);
    }
    __builtin_amdgcn_fence(__ATOMIC_ACQUIRE, "agent");  // invalidate stale L1/L2 lines
  }
  __syncthreads();
}

// ---------- persistent recurrence ----------
// 256 blocks x 256 thr, 1 block/CU. blk = bgrp*64 + hgrp (4 blocks sharing a
// weight slice land on the same XCD). Wave: 16 interleaved gate cols
// (4 hidden x {i,f,c,o}) x 16 batches; U/V slices live in VGPRs for all 512 steps.
__global__ __launch_bounds__(256, 1) void lstm_recur(
    const float* __restrict__ x,        // [B][T][I] fp32
    const _Float16* __restrict__ Ubt,   // [4096][512]  row 4n+q = U_q[:,n]
    const _Float16* __restrict__ Vt,    // [4096][1024] row 4n+q = V_q[:,n]
    const float* __restrict__ biasw,    // [4096] interleaved
    float* __restrict__ out,            // hidden_seq | h_T | c_T
    _Float16* __restrict__ hbuf,        // [2][64][1024] f16 double buffer
    unsigned* __restrict__ bar)
{
  const int tid  = threadIdx.x;
  const int wv   = tid >> 6;
  const int lane = tid & 63;
  const int lc   = lane & 15;     // col-in-wave / A-row sel
  const int lk   = lane >> 4;     // k-group
  const int q    = lc & 3;        // gate id (0=i,1=f,2=g,3=o)
  const int blk  = blockIdx.x;
  const int bgrp = blk >> 6;      // 0..3
  const int hgrp = blk & 63;      // 0..63
  const int col0 = hgrp * 64 + wv * 16;
  const int b0   = bgrp * 16;

  // stationary weight fragments in registers (survive all fences)
  f16x8 bU[16];
  f16x8 bV[32];
  {
    const _Float16* up = Ubt + (size_t)(col0 + lc) * I_SZ + lk * 8;
    #pragma unroll
    for (int ks = 0; ks < 16; ++ks) bU[ks] = *(const f16x8*)(up + ks * 32);
    const _Float16* vp = Vt + (size_t)(col0 + lc) * H_SZ + lk * 8;
    #pragma unroll
    for (int ks = 0; ks < 32; ++ks) bV[ks] = *(const f16x8*)(vp + ks * 32);
  }
  const float bias_v = biasw[col0 + lc];
  const int n_glob = hgrp * 16 + wv * 4 + (lc >> 2);
  const size_t HO = (size_t)B_SZ * T_SZ * H_SZ;
  const size_t CO = HO + (size_t)B_SZ * H_SZ;

  float cst[4] = {0.f, 0.f, 0.f, 0.f};  // c-state, redundant x4 q-lanes

  for (int t = 0; t < T_SZ; ++t) {
    if (t) gbar(bar, blk);  // h(t) from step t-1 now visible everywhere

    const _Float16* hcur  = hbuf + (size_t)(t & 1) * (B_SZ * H_SZ);
    _Float16*       hnext = hbuf + (size_t)((t + 1) & 1) * (B_SZ * H_SZ);

    f32x4 acc[4];
    acc[0] = f32x4{bias_v, bias_v, bias_v, bias_v};
    acc[1] = f32x4{0.f, 0.f, 0.f, 0.f};
    acc[2] = f32x4{0.f, 0.f, 0.f, 0.f};
    acc[3] = f32x4{0.f, 0.f, 0.f, 0.f};

    // x projection: A rows = batch, K = I, fp32 -> f16 on the fly
    const float* xp = x + ((size_t)(b0 + lc) * T_SZ + t) * I_SZ + lk * 8;
    #pragma unroll
    for (int ks = 0; ks < 16; ++ks) {
      const float4 xa = *(const float4*)(xp + ks * 32);
      const float4 xb = *(const float4*)(xp + ks * 32 + 4);
      f16x8 a = { (_Float16)xa.x, (_Float16)xa.y, (_Float16)xa.z, (_Float16)xa.w,
                  (_Float16)xb.x, (_Float16)xb.y, (_Float16)xb.z, (_Float16)xb.w };
      acc[ks & 3] = __builtin_amdgcn_mfma_f32_16x16x32_f16(a, bU[ks], acc[ks & 3], 0, 0, 0);
    }
    // h projection: K = H
    const _Float16* hp = hcur + (size_t)(b0 + lc) * H_SZ + lk * 8;
    #pragma unroll
    for (int ks = 0; ks < 32; ++ks) {
      const f16x8 a = *(const f16x8*)(hp + ks * 32);
      acc[ks & 3] = __builtin_amdgcn_mfma_f32_16x16x32_f16(a, bV[ks], acc[ks & 3], 0, 0, 0);
    }

    // elementwise: lane holds gate q of hidden n_glob for D rows b0+lk*4+r
    #pragma unroll
    for (int r = 0; r < 4; ++r) {
      const float v  = acc[0][r] + acc[1][r] + acc[2][r] + acc[3][r];
      const float sc = (q == 2) ? 2.f : 1.f;
      const float s  = 1.f / (1.f + __expf(-sc * v));
      const float av = (q == 2) ? (2.f * s - 1.f) : s;   // tanh via 2*sigm(2x)-1
      const float x1 = __shfl_xor(av, 1);
      const float x2 = __shfl_xor(av, 2);
      const float x3 = __shfl_xor(av, 3);
      const float gi = (q == 0) ? av : (q == 1) ? x1 : (q == 2) ? x2 : x3;
      const int m1 = q ^ 1;
      const float gf = (m1 == 0) ? av : (m1 == 1) ? x1 : (m1 == 2) ? x2 : x3;
      const int m2 = q ^ 2;
      const float gg = (m2 == 0) ? av : (m2 == 1) ? x1 : (m2 == 2) ? x2 : x3;
      const int m3 = q ^ 3;
      const float go = (m3 == 0) ? av : (m3 == 1) ? x1 : (m3 == 2) ? x2 : x3;
      const float cn = gf * cst[r] + gi * gg;
      const float s2 = 1.f / (1.f + __expf(-2.f * cn));
      const float hn = go * (2.f * s2 - 1.f);
      cst[r] = cn;
      if (q == 0) {
        const int b = b0 + lk * 4 + r;
        out[(size_t)b * (T_SZ * H_SZ) + (size_t)t * H_SZ + n_glob] = hn;
        hnext[(size_t)b * H_SZ + n_glob] = (_Float16)hn;
        if (t == T_SZ - 1) {
          out[HO + (size_t)b * H_SZ + n_glob] = hn;
          out[CO + (size_t)b * H_SZ + n_glob] = cn;
        }
      }
    }
  }
}

extern "C" void kernel_launch(void* const* d_in, const int* in_sizes, int n_in,
                              void* d_out, int out_size, void* d_ws, size_t ws_size,
                              hipStream_t stream) {
  const float* x = (const float*)d_in[0];
  const float* U[4]  = {(const float*)d_in[1], (const float*)d_in[4],
                        (const float*)d_in[7], (const float*)d_in[10]};
  const float* V[4]  = {(const float*)d_in[2], (const float*)d_in[5],
                        (const float*)d_in[8], (const float*)d_in[11]};
  const float* bb[4] = {(const float*)d_in[3], (const float*)d_in[6],
                        (const float*)d_in[9], (const float*)d_in[12]};
  float* out = (float*)d_out;

  char* p = (char*)d_ws;
  _Float16* Ubt = (_Float16*)p; p += (size_t)G4 * I_SZ * 2;          // 4 MB
  _Float16* Vt  = (_Float16*)p; p += (size_t)G4 * H_SZ * 2;          // 8 MB
  float*    biasw = (float*)p;  p += (size_t)G4 * 4;                 // 16 KB
  _Float16* hbuf  = (_Float16*)p; p += (size_t)2 * B_SZ * H_SZ * 2;  // 256 KB
  unsigned* bar   = (unsigned*)p;                                    // 4 KB

  for (int qq = 0; qq < 4; ++qq)
    hipLaunchKernelGGL(trans_kernel, dim3(16, 8), dim3(256), 0, stream, U[qq], Ubt, I_SZ, qq);
  for (int qq = 0; qq < 4; ++qq)
    hipLaunchKernelGGL(trans_kernel, dim3(16, 16), dim3(256), 0, stream, V[qq], Vt, H_SZ, qq);
  hipLaunchKernelGGL(bias_kernel, dim3(16), dim3(256), 0, stream, bb[0], bb[1], bb[2], bb[3], biasw);

  // h(0) = 0 (buffer 0 only is read at t=0) and barrier state = 0, every call
  hipMemsetAsync(hbuf, 0, (size_t)B_SZ * H_SZ * 2, stream);
  hipMemsetAsync(bar, 0, 4096, stream);

  hipLaunchKernelGGL(lstm_recur, dim3(NBLK), dim3(256), 0, stream,
                     x, Ubt, Vt, biasw, out, hbuf, bar);
}

// Round 4
// 8322.919 us; speedup vs baseline: 1.3461x; 1.3461x over previous
//
#include <hip/hip_runtime.h>

typedef __attribute__((ext_vector_type(8))) _Float16 f16x8;
typedef __attribute__((ext_vector_type(4))) float f32x4;

#define B_SZ 64
#define T_SZ 512
#define I_SZ 512
#define H_SZ 1024
#define G4   4096
#define NBLK 256

// ---------- prep: transpose + gate-interleave weights ----------
// src: [R][1024] fp32 (gate q's U or V). dst: [4096][R] f16, dst[4*n+q][r] = src[r][n]
__global__ void trans_kernel(const float* __restrict__ src, _Float16* __restrict__ dst,
                             int R, int q) {
  __shared__ float tile[64][65];
  const int n0 = blockIdx.x * 64;
  const int r0 = blockIdx.y * 64;
  const int x = threadIdx.x & 63, y = threadIdx.x >> 6;
  #pragma unroll
  for (int it = 0; it < 16; ++it) {
    int r = y * 16 + it;
    tile[r][x] = src[(size_t)(r0 + r) * H_SZ + n0 + x];
  }
  __syncthreads();
  #pragma unroll
  for (int it = 0; it < 16; ++it) {
    int rn = y * 16 + it;
    dst[(size_t)(4 * (n0 + rn) + q) * R + r0 + x] = (_Float16)tile[x][rn];
  }
}

// ---------- prep: interleave bias ----------
__global__ void bias_kernel(const float* __restrict__ b0, const float* __restrict__ b1,
                            const float* __restrict__ b2, const float* __restrict__ b3,
                            float* __restrict__ dst) {
  int g = blockIdx.x * blockDim.x + threadIdx.x;
  if (g >= G4) return;
  int q = g & 3, n = g >> 2;
  const float* s = (q == 0) ? b0 : (q == 1) ? b1 : (q == 2) ? b2 : b3;
  dst[g] = s[n];
}

// h store: write-through to LLC (coherence point), no dirty L2 line
__device__ __forceinline__ void store_h_llc(_Float16* p, _Float16 v) {
  asm volatile("global_store_short %0, %1, off sc0 sc1" :: "v"(p), "v"(v) : "memory");
}

// ---------- persistent recurrence, flag-based sync, zero cache maintenance ----------
// 256 blocks x 256 thr, 1/CU. blk = bgrp*64 + hgrp; blk%8 == hgrp%8 so the 4
// batch-group copies of a weight slice share one XCD -> slice stays L2-resident
// for all 512 steps (no invalidates!). Wave: 16 interleaved gate cols
// (4 hidden x {i,f,c,o}) x 16 batch rows. h crosses XCDs via LLC (sc0 sc1).
__global__ __launch_bounds__(256, 1) void lstm_recur(
    const float* __restrict__ x,        // [B][T][I] fp32
    const _Float16* __restrict__ Ubt,   // [4096][512]  row 4n+q = U_q[:,n]
    const _Float16* __restrict__ Vt,    // [4096][1024] row 4n+q = V_q[:,n]
    const float* __restrict__ biasw,    // [4096] interleaved
    float* __restrict__ out,            // hidden_seq | h_T | c_T
    _Float16* __restrict__ hbuf,        // [2][64][1024] f16 double buffer
    unsigned* __restrict__ bar)         // per-bgrp: cnt @ bgrp*64, gen @ bgrp*64+32
{
  const int tid  = threadIdx.x;
  const int wv   = tid >> 6;
  const int lane = tid & 63;
  const int lc   = lane & 15;     // col-in-wave / A-row sel
  const int lk   = lane >> 4;     // k-group
  const int q    = lc & 3;        // gate id (0=i,1=f,2=g,3=o)
  const int blk  = blockIdx.x;
  const int bgrp = blk >> 6;      // 0..3  (independent batch chains)
  const int hgrp = blk & 63;      // 0..63
  const int col0 = hgrp * 64 + wv * 16;
  const int b0   = bgrp * 16;

  unsigned* cnt = bar + bgrp * 64;        // monotone arrival counter
  unsigned* gen = bar + bgrp * 64 + 32;   // published generation

  // per-wave weight slices; compiler keeps or reloads from (now warm) L2
  f16x8 bU[16];
  f16x8 bV[32];
  {
    const _Float16* up = Ubt + (size_t)(col0 + lc) * I_SZ + lk * 8;
    #pragma unroll
    for (int ks = 0; ks < 16; ++ks) bU[ks] = *(const f16x8*)(up + ks * 32);
    const _Float16* vp = Vt + (size_t)(col0 + lc) * H_SZ + lk * 8;
    #pragma unroll
    for (int ks = 0; ks < 32; ++ks) bV[ks] = *(const f16x8*)(vp + ks * 32);
  }
  const float bias_v = biasw[col0 + lc];
  const int n_glob = hgrp * 16 + wv * 4 + (lc >> 2);
  const size_t HO = (size_t)B_SZ * T_SZ * H_SZ;
  const size_t CO = HO + (size_t)B_SZ * H_SZ;

  float cst[4] = {0.f, 0.f, 0.f, 0.f};  // c-state, redundant x4 q-lanes

  for (int t = 0; t < T_SZ; ++t) {
    const _Float16* hcur  = hbuf + (size_t)(t & 1) * (B_SZ * H_SZ);
    _Float16*       hnext = hbuf + (size_t)((t + 1) & 1) * (B_SZ * H_SZ);

    f32x4 acc[4];
    acc[0] = f32x4{bias_v, bias_v, bias_v, bias_v};
    acc[1] = f32x4{0.f, 0.f, 0.f, 0.f};
    acc[2] = f32x4{0.f, 0.f, 0.f, 0.f};
    acc[3] = f32x4{0.f, 0.f, 0.f, 0.f};

    // ---- x projection FIRST (independent of h(t)) — hides producer skew ----
    const float* xp = x + ((size_t)(b0 + lc) * T_SZ + t) * I_SZ + lk * 8;
    #pragma unroll
    for (int ks = 0; ks < 16; ++ks) {
      const float4 xa = *(const float4*)(xp + ks * 32);
      const float4 xb = *(const float4*)(xp + ks * 32 + 4);
      f16x8 a = { (_Float16)xa.x, (_Float16)xa.y, (_Float16)xa.z, (_Float16)xa.w,
                  (_Float16)xb.x, (_Float16)xb.y, (_Float16)xb.z, (_Float16)xb.w };
      acc[ks & 3] = __builtin_amdgcn_mfma_f32_16x16x32_f16(a, bU[ks], acc[ks & 3], 0, 0, 0);
    }

    // ---- wait for h(t) to be published (t=0: memset, visible at launch) ----
    if (t) {
      while (__hip_atomic_load(gen, __ATOMIC_RELAXED, __HIP_MEMORY_SCOPE_SYSTEM) < (unsigned)t)
        __builtin_amdgcn_s_sleep(1);
      __builtin_amdgcn_sched_barrier(0);  // keep h loads below the spin
    }

    // ---- h projection: h read from LLC (system-scope, bypasses L1/L2) ----
    const unsigned long long* hb =
        (const unsigned long long*)(hcur + (size_t)(b0 + lc) * H_SZ + lk * 8);
    #pragma unroll
    for (int ks = 0; ks < 32; ++ks) {
      union { unsigned long long qw[2]; f16x8 v; } u;
      u.qw[0] = __hip_atomic_load(hb + ks * 8 + 0, __ATOMIC_RELAXED, __HIP_MEMORY_SCOPE_SYSTEM);
      u.qw[1] = __hip_atomic_load(hb + ks * 8 + 1, __ATOMIC_RELAXED, __HIP_MEMORY_SCOPE_SYSTEM);
      acc[ks & 3] = __builtin_amdgcn_mfma_f32_16x16x32_f16(u.v, bV[ks], acc[ks & 3], 0, 0, 0);
    }

    // ---- gates: lane holds gate q of hidden n_glob for D rows b0+lk*4+r ----
    #pragma unroll
    for (int r = 0; r < 4; ++r) {
      const float v  = acc[0][r] + acc[1][r] + acc[2][r] + acc[3][r];
      const float sc = (q == 2) ? 2.f : 1.f;
      const float s  = 1.f / (1.f + __expf(-sc * v));
      const float av = (q == 2) ? (2.f * s - 1.f) : s;   // tanh via 2*sigm(2x)-1
      const float x1 = __shfl_xor(av, 1);
      const float x2 = __shfl_xor(av, 2);
      const float x3 = __shfl_xor(av, 3);
      const float gi = (q == 0) ? av : (q == 1) ? x1 : (q == 2) ? x2 : x3;
      const int m1 = q ^ 1;
      const float gf = (m1 == 0) ? av : (m1 == 1) ? x1 : (m1 == 2) ? x2 : x3;
      const int m2 = q ^ 2;
      const float gg = (m2 == 0) ? av : (m2 == 1) ? x1 : (m2 == 2) ? x2 : x3;
      const int m3 = q ^ 3;
      const float go = (m3 == 0) ? av : (m3 == 1) ? x1 : (m3 == 2) ? x2 : x3;
      const float cn = gf * cst[r] + gi * gg;
      const float s2 = 1.f / (1.f + __expf(-2.f * cn));
      const float hn = go * (2.f * s2 - 1.f);
      cst[r] = cn;
      if (q == 0) {
        const int b = b0 + lk * 4 + r;
        out[(size_t)b * (T_SZ * H_SZ) + (size_t)t * H_SZ + n_glob] = hn;
        store_h_llc(hnext + (size_t)b * H_SZ + n_glob, (_Float16)hn);
        if (t == T_SZ - 1) {
          out[HO + (size_t)b * H_SZ + n_glob] = hn;
          out[CO + (size_t)b * H_SZ + n_glob] = cn;
        }
      }
    }

    // ---- publish: drain h stores to LLC, then arrive ----
    asm volatile("s_waitcnt vmcnt(0)" ::: "memory");
    __syncthreads();
    if (tid == 0) {
      unsigned a = __hip_atomic_fetch_add(cnt, 1u, __ATOMIC_RELAXED, __HIP_MEMORY_SCOPE_SYSTEM);
      if (a == (unsigned)(64 * (t + 1) - 1))   // last of the 64 blocks this step
        __hip_atomic_store(gen, (unsigned)(t + 1), __ATOMIC_RELAXED, __HIP_MEMORY_SCOPE_SYSTEM);
    }
  }
}

extern "C" void kernel_launch(void* const* d_in, const int* in_sizes, int n_in,
                              void* d_out, int out_size, void* d_ws, size_t ws_size,
                              hipStream_t stream) {
  const float* x = (const float*)d_in[0];
  const float* U[4]  = {(const float*)d_in[1], (const float*)d_in[4],
                        (const float*)d_in[7], (const float*)d_in[10]};
  const float* V[4]  = {(const float*)d_in[2], (const float*)d_in[5],
                        (const float*)d_in[8], (const float*)d_in[11]};
  const float* bb[4] = {(const float*)d_in[3], (const float*)d_in[6],
                        (const float*)d_in[9], (const float*)d_in[12]};
  float* out = (float*)d_out;

  char* p = (char*)d_ws;
  _Float16* Ubt = (_Float16*)p; p += (size_t)G4 * I_SZ * 2;          // 4 MB
  _Float16* Vt  = (_Float16*)p; p += (size_t)G4 * H_SZ * 2;          // 8 MB
  float*    biasw = (float*)p;  p += (size_t)G4 * 4;                 // 16 KB
  _Float16* hbuf  = (_Float16*)p; p += (size_t)2 * B_SZ * H_SZ * 2;  // 256 KB
  unsigned* bar   = (unsigned*)p;                                    // 4 KB

  for (int qq = 0; qq < 4; ++qq)
    hipLaunchKernelGGL(trans_kernel, dim3(16, 8), dim3(256), 0, stream, U[qq], Ubt, I_SZ, qq);
  for (int qq = 0; qq < 4; ++qq)
    hipLaunchKernelGGL(trans_kernel, dim3(16, 16), dim3(256), 0, stream, V[qq], Vt, H_SZ, qq);
  hipLaunchKernelGGL(bias_kernel, dim3(16), dim3(256), 0, stream, bb[0], bb[1], bb[2], bb[3], biasw);

  // h(0) = 0 (buffer 0 is read at t=0); barrier counters = 0 (graph-replay safe)
  hipMemsetAsync(hbuf, 0, (size_t)B_SZ * H_SZ * 2, stream);
  hipMemsetAsync(bar, 0, 4096, stream);

  hipLaunchKernelGGL(lstm_recur, dim3(NBLK), dim3(256), 0, stream,
                     x, Ubt, Vt, biasw, out, hbuf, bar);
}

// Round 5
// 4819.415 us; speedup vs baseline: 2.3247x; 1.7270x over previous
//
#include <hip/hip_runtime.h>

typedef __attribute__((ext_vector_type(8))) _Float16 f16x8;
typedef __attribute__((ext_vector_type(4))) float f32x4;
typedef __attribute__((ext_vector_type(2))) unsigned int u32x2;

#define B_SZ 64
#define T_SZ 512
#define I_SZ 512
#define H_SZ 1024
#define G4   4096
#define NBLK 256

// ---------- prep: transpose + gate-interleave weights ----------
// src: [R][1024] fp32 (gate q's U or V). dst: [4096][R] f16, dst[4*n+q][r] = src[r][n]
__global__ void trans_kernel(const float* __restrict__ src, _Float16* __restrict__ dst,
                             int R, int q) {
  __shared__ float tile[64][65];
  const int n0 = blockIdx.x * 64;
  const int r0 = blockIdx.y * 64;
  const int x = threadIdx.x & 63, y = threadIdx.x >> 6;
  #pragma unroll
  for (int it = 0; it < 16; ++it) {
    int r = y * 16 + it;
    tile[r][x] = src[(size_t)(r0 + r) * H_SZ + n0 + x];
  }
  __syncthreads();
  #pragma unroll
  for (int it = 0; it < 16; ++it) {
    int rn = y * 16 + it;
    dst[(size_t)(4 * (n0 + rn) + q) * R + r0 + x] = (_Float16)tile[x][rn];
  }
}

// ---------- prep: interleave bias ----------
__global__ void bias_kernel(const float* __restrict__ b0, const float* __restrict__ b1,
                            const float* __restrict__ b2, const float* __restrict__ b3,
                            float* __restrict__ dst) {
  int g = blockIdx.x * blockDim.x + threadIdx.x;
  if (g >= G4) return;
  int q = g & 3, n = g >> 2;
  const float* s = (q == 0) ? b0 : (q == 1) ? b1 : (q == 2) ? b2 : b3;
  dst[g] = s[n];
}

__device__ __forceinline__ float h2f(unsigned short u) {
  union { unsigned short s; _Float16 h; } c; c.s = u; return (float)c.h;
}
__device__ __forceinline__ unsigned short f2h(float f) {
  union { unsigned short s; _Float16 h; } c; c.h = (_Float16)f; return c.s;
}

// ---------- persistent recurrence ----------
// 256 blocks x 256 thr, 1/CU. blk = hgrp*4 + bgrp -> XCD(blk%8) = 4*(hgrp&1)+bgrp:
// each batch-chain (bgrp) is pinned to XCD pair {bgrp, bgrp+4} -> x streamed from
// HBM only 2x. Weights live in VGPRs (asm-pinned) for all 512 steps. h crosses
// XCDs via LLC (sc0 sc1), staged per-block into swizzled LDS once per step.
__global__ __launch_bounds__(256, 1) void lstm_recur(
    const float* __restrict__ x,        // [B][T][I] fp32
    const _Float16* __restrict__ Ubt,   // [4096][512]  row 4n+q = U_q[:,n]
    const _Float16* __restrict__ Vt,    // [4096][1024] row 4n+q = V_q[:,n]
    const float* __restrict__ biasw,    // [4096] interleaved
    float* __restrict__ out,            // hidden_seq | h_T | c_T
    _Float16* __restrict__ hbuf,        // [2][64][1024] f16 double buffer
    unsigned* __restrict__ bar)         // per-chain arrival tree (monotone)
{
  __shared__ __align__(16) char hsh[32768];   // h slice [16][1024] f16, XOR-swizzled

  const int tid  = threadIdx.x;
  const int wv   = tid >> 6;
  const int lane = tid & 63;
  const int lc   = lane & 15;     // col-in-wave / A-row sel
  const int lk   = lane >> 4;     // k-group
  const int q    = lc & 3;        // gate id (0=i,1=f,2=g,3=o)
  const int p    = lc >> 2;       // quad id (col within 4-col group)
  const int blk  = blockIdx.x;
  const int bgrp = blk & 3;       // batch chain, pinned to XCD pair
  const int hgrp = blk >> 2;      // 0..63
  const int col0 = hgrp * 64 + wv * 16;
  const int b0   = bgrp * 16;

  unsigned* cnt  = bar + bgrp * 1024 + (hgrp >> 3) * 32;  // 8 groups of 8 blocks
  unsigned* root = bar + bgrp * 1024 + 8 * 32;
  unsigned* gen  = bar + bgrp * 1024 + 9 * 32;

  // ---- stationary weights: load once, pin in VGPRs via opaque asm ----
  f16x8 bU[16];
  f16x8 bV[32];
  {
    const _Float16* up = Ubt + (size_t)(col0 + lc) * I_SZ + lk * 8;
    #pragma unroll
    for (int ks = 0; ks < 16; ++ks) bU[ks] = *(const f16x8*)(up + ks * 32);
    const _Float16* vp = Vt + (size_t)(col0 + lc) * H_SZ + lk * 8;
    #pragma unroll
    for (int ks = 0; ks < 32; ++ks) bV[ks] = *(const f16x8*)(vp + ks * 32);
  }
  #pragma unroll
  for (int ks = 0; ks < 16; ++ks) asm volatile("" : "+v"(bU[ks]));
  #pragma unroll
  for (int ks = 0; ks < 32; ++ks) asm volatile("" : "+v"(bV[ks]));

  const float bias_v = biasw[col0 + lc];
  const int n_glob = hgrp * 16 + wv * 4 + p;
  const int cb     = hgrp * 16 + wv * 4;        // 4-col group base
  const size_t HO = (size_t)B_SZ * T_SZ * H_SZ;
  const size_t CO = HO + (size_t)B_SZ * H_SZ;

  float cst[4] = {0.f, 0.f, 0.f, 0.f};  // c-state, redundant x4 q-lanes

  for (int t = 0; t < T_SZ; ++t) {
    const _Float16* hcur  = hbuf + (size_t)(t & 1) * (B_SZ * H_SZ);
    _Float16*       hnext = hbuf + (size_t)((t + 1) & 1) * (B_SZ * H_SZ);

    f32x4 acc[4];
    acc[0] = f32x4{bias_v, bias_v, bias_v, bias_v};
    acc[1] = f32x4{0.f, 0.f, 0.f, 0.f};
    acc[2] = f32x4{0.f, 0.f, 0.f, 0.f};
    acc[3] = f32x4{0.f, 0.f, 0.f, 0.f};

    // ---- x projection (independent of h(t)) — hides producer skew ----
    const float* xp = x + ((size_t)(b0 + lc) * T_SZ + t) * I_SZ + lk * 8;
    #pragma unroll
    for (int ks = 0; ks < 16; ++ks) {
      const float4 xa = *(const float4*)(xp + ks * 32);
      const float4 xb = *(const float4*)(xp + ks * 32 + 4);
      f16x8 a = { (_Float16)xa.x, (_Float16)xa.y, (_Float16)xa.z, (_Float16)xa.w,
                  (_Float16)xb.x, (_Float16)xb.y, (_Float16)xb.z, (_Float16)xb.w };
      acc[ks & 3] = __builtin_amdgcn_mfma_f32_16x16x32_f16(a, bU[ks], acc[ks & 3], 0, 0, 0);
    }

    // ---- leader-only wait for h(t) ----
    if (t) {
      if (tid == 0) {
        while (__hip_atomic_load(gen, __ATOMIC_RELAXED, __HIP_MEMORY_SCOPE_SYSTEM) < (unsigned)t)
          __builtin_amdgcn_s_sleep(2);
      }
      __syncthreads();
    }

    // ---- cooperative h fetch: 32 KB slice -> swizzled LDS (bypass L1/L2) ----
    {
      const char* src = (const char*)(hcur + (size_t)b0 * H_SZ) + tid * 16;
      f16x8 st0, st1, st2, st3, st4, st5, st6, st7;
      asm volatile("global_load_dwordx4 %0, %1, off sc0 sc1" : "=v"(st0) : "v"(src)          : "memory");
      asm volatile("global_load_dwordx4 %0, %1, off sc0 sc1" : "=v"(st1) : "v"(src + 4096)   : "memory");
      asm volatile("global_load_dwordx4 %0, %1, off sc0 sc1" : "=v"(st2) : "v"(src + 8192)   : "memory");
      asm volatile("global_load_dwordx4 %0, %1, off sc0 sc1" : "=v"(st3) : "v"(src + 12288)  : "memory");
      asm volatile("global_load_dwordx4 %0, %1, off sc0 sc1" : "=v"(st4) : "v"(src + 16384)  : "memory");
      asm volatile("global_load_dwordx4 %0, %1, off sc0 sc1" : "=v"(st5) : "v"(src + 20480)  : "memory");
      asm volatile("global_load_dwordx4 %0, %1, off sc0 sc1" : "=v"(st6) : "v"(src + 24576)  : "memory");
      asm volatile("global_load_dwordx4 %0, %1, off sc0 sc1" : "=v"(st7) : "v"(src + 28672)  : "memory");
      asm volatile("s_waitcnt vmcnt(0)" ::: "memory");
      __builtin_amdgcn_sched_barrier(0);
      f16x8 st[8] = {st0, st1, st2, st3, st4, st5, st6, st7};
      #pragma unroll
      for (int j = 0; j < 8; ++j) {
        const int byteoff = j * 4096 + tid * 16;
        const int row  = byteoff >> 11;
        const int colb = byteoff & 2047;
        *(f16x8*)(hsh + ((row << 11) | (colb ^ ((row & 7) << 4)))) = st[j];
      }
    }
    __syncthreads();

    // ---- h projection from LDS (2-way bank aliasing only — free) ----
    #pragma unroll
    for (int ks = 0; ks < 32; ++ks) {
      const int a = (lc << 11) | ((lk * 16 + ks * 64) ^ ((lc & 7) << 4));
      const f16x8 hv = *(const f16x8*)(hsh + a);
      acc[ks & 3] = __builtin_amdgcn_mfma_f32_16x16x32_f16(hv, bV[ks], acc[ks & 3], 0, 0, 0);
    }

    // ---- gates: lane holds gate q of hidden n_glob for rows b0+lk*4+r ----
    float hnf[4];
    #pragma unroll
    for (int r = 0; r < 4; ++r) {
      const float v  = acc[0][r] + acc[1][r] + acc[2][r] + acc[3][r];
      const float sc = (q == 2) ? 2.f : 1.f;
      const float s  = 1.f / (1.f + __expf(-sc * v));
      const float av = (q == 2) ? (2.f * s - 1.f) : s;   // tanh via 2*sigm(2x)-1
      const float x1 = __shfl_xor(av, 1);
      const float x2 = __shfl_xor(av, 2);
      const float x3 = __shfl_xor(av, 3);
      const float gi = (q == 0) ? av : (q == 1) ? x1 : (q == 2) ? x2 : x3;
      const int m1 = q ^ 1;
      const float gf = (m1 == 0) ? av : (m1 == 1) ? x1 : (m1 == 2) ? x2 : x3;
      const int m2 = q ^ 2;
      const float gg = (m2 == 0) ? av : (m2 == 1) ? x1 : (m2 == 2) ? x2 : x3;
      const int m3 = q ^ 3;
      const float go = (m3 == 0) ? av : (m3 == 1) ? x1 : (m3 == 2) ? x2 : x3;
      const float cn = gf * cst[r] + gi * gg;
      const float s2 = 1.f / (1.f + __expf(-2.f * cn));
      hnf[r] = go * (2.f * s2 - 1.f);
      cst[r] = cn;
    }

    // ---- 4x4 shuffle transpose: lane p gets row (b0+lk*4+p), cols cb..cb+3 ----
    const unsigned c01 = (unsigned)f2h(hnf[0]) | ((unsigned)f2h(hnf[1]) << 16);
    const unsigned c23 = (unsigned)f2h(hnf[2]) | ((unsigned)f2h(hnf[3]) << 16);
    const unsigned t01 = __shfl_xor(c01, 4);
    const unsigned t23 = __shfl_xor(c23, 4);
    unsigned r01, r23;
    if (p & 1) { r01 = (t01 >> 16) | (c01 & 0xffff0000u); r23 = (t23 >> 16) | (c23 & 0xffff0000u); }
    else       { r01 = (c01 & 0xffffu) | (t01 << 16);     r23 = (c23 & 0xffffu) | (t23 << 16); }
    const unsigned x01 = __shfl_xor(r01, 8);
    const unsigned x23 = __shfl_xor(r23, 8);
    u32x2 hw;
    if (p < 2) { hw.x = r01; hw.y = x01; }
    else       { hw.x = x23; hw.y = r23; }

    if (q == 0) {
      const int row = b0 + lk * 4 + p;
      // hidden_seq: 16B fp32 store (f16-rounded; err << threshold)
      f32x4 of = { h2f((unsigned short)(hw.x & 0xffffu)), h2f((unsigned short)(hw.x >> 16)),
                   h2f((unsigned short)(hw.y & 0xffffu)), h2f((unsigned short)(hw.y >> 16)) };
      *(f32x4*)(out + (size_t)row * (T_SZ * H_SZ) + (size_t)t * H_SZ + cb) = of;
      if (t < T_SZ - 1) {
        _Float16* hp2 = hnext + (size_t)row * H_SZ + cb;
        asm volatile("global_store_dwordx2 %0, %1, off sc0 sc1" :: "v"(hp2), "v"(hw) : "memory");
      } else {
        // exact fp32 h_T / c_T (scattered, once)
        #pragma unroll
        for (int r = 0; r < 4; ++r) {
          const int b = b0 + lk * 4 + r;
          out[HO + (size_t)b * H_SZ + n_glob] = hnf[r];
          out[CO + (size_t)b * H_SZ + n_glob] = cst[r];
        }
      }
    }

    // ---- publish: drain h stores, then tree arrival (leader only) ----
    if (t < T_SZ - 1) {
      asm volatile("s_waitcnt vmcnt(0)" ::: "memory");
      __syncthreads();
      if (tid == 0) {
        unsigned a = __hip_atomic_fetch_add(cnt, 1u, __ATOMIC_RELAXED, __HIP_MEMORY_SCOPE_SYSTEM);
        if (a == 8u * (unsigned)(t + 1) - 1u) {
          unsigned rr = __hip_atomic_fetch_add(root, 1u, __ATOMIC_RELAXED, __HIP_MEMORY_SCOPE_SYSTEM);
          if (rr == 8u * (unsigned)(t + 1) - 1u)
            __hip_atomic_store(gen, (unsigned)(t + 1), __ATOMIC_RELAXED, __HIP_MEMORY_SCOPE_SYSTEM);
        }
      }
    }
  }
}

extern "C" void kernel_launch(void* const* d_in, const int* in_sizes, int n_in,
                              void* d_out, int out_size, void* d_ws, size_t ws_size,
                              hipStream_t stream) {
  const float* x = (const float*)d_in[0];
  const float* U[4]  = {(const float*)d_in[1], (const float*)d_in[4],
                        (const float*)d_in[7], (const float*)d_in[10]};
  const float* V[4]  = {(const float*)d_in[2], (const float*)d_in[5],
                        (const float*)d_in[8], (const float*)d_in[11]};
  const float* bb[4] = {(const float*)d_in[3], (const float*)d_in[6],
                        (const float*)d_in[9], (const float*)d_in[12]};
  float* out = (float*)d_out;

  char* p = (char*)d_ws;
  _Float16* Ubt = (_Float16*)p; p += (size_t)G4 * I_SZ * 2;          // 4 MB
  _Float16* Vt  = (_Float16*)p; p += (size_t)G4 * H_SZ * 2;          // 8 MB
  float*    biasw = (float*)p;  p += (size_t)G4 * 4;                 // 16 KB
  _Float16* hbuf  = (_Float16*)p; p += (size_t)2 * B_SZ * H_SZ * 2;  // 256 KB
  unsigned* bar   = (unsigned*)p;                                    // 16 KB

  for (int qq = 0; qq < 4; ++qq)
    hipLaunchKernelGGL(trans_kernel, dim3(16, 8), dim3(256), 0, stream, U[qq], Ubt, I_SZ, qq);
  for (int qq = 0; qq < 4; ++qq)
    hipLaunchKernelGGL(trans_kernel, dim3(16, 16), dim3(256), 0, stream, V[qq], Vt, H_SZ, qq);
  hipLaunchKernelGGL(bias_kernel, dim3(16), dim3(256), 0, stream, bb[0], bb[1], bb[2], bb[3], biasw);

  // h(0) = 0 (buffer 0 read at t=0); barrier tree = 0 (graph-replay safe)
  hipMemsetAsync(hbuf, 0, (size_t)B_SZ * H_SZ * 2, stream);
  hipMemsetAsync(bar, 0, 16384, stream);

  hipLaunchKernelGGL(lstm_recur, dim3(NBLK), dim3(256), 0, stream,
                     x, Ubt, Vt, biasw, out, hbuf, bar);
}

// Round 6
// 2308.890 us; speedup vs baseline: 4.8524x; 2.0873x over previous
//
#include <hip/hip_runtime.h>

typedef __attribute__((ext_vector_type(8))) _Float16 f16x8;
typedef __attribute__((ext_vector_type(4))) float f32x4;
typedef __attribute__((ext_vector_type(2))) unsigned int u32x2;

#define B_SZ 64
#define T_SZ 512
#define I_SZ 512
#define H_SZ 1024
#define G4   4096
#define NBLK 256

// ---------- prep: transpose + gate-interleave weights ----------
// src: [R][1024] fp32 (gate q's U or V). dst: [4096][R] f16, dst[4*n+q][r] = src[r][n]
__global__ void trans_kernel(const float* __restrict__ src, _Float16* __restrict__ dst,
                             int R, int q) {
  __shared__ float tile[64][65];
  const int n0 = blockIdx.x * 64;
  const int r0 = blockIdx.y * 64;
  const int x = threadIdx.x & 63, y = threadIdx.x >> 6;
  #pragma unroll
  for (int it = 0; it < 16; ++it) {
    int r = y * 16 + it;
    tile[r][x] = src[(size_t)(r0 + r) * H_SZ + n0 + x];
  }
  __syncthreads();
  #pragma unroll
  for (int it = 0; it < 16; ++it) {
    int rn = y * 16 + it;
    dst[(size_t)(4 * (n0 + rn) + q) * R + r0 + x] = (_Float16)tile[x][rn];
  }
}

// ---------- prep: interleave bias ----------
__global__ void bias_kernel(const float* __restrict__ b0, const float* __restrict__ b1,
                            const float* __restrict__ b2, const float* __restrict__ b3,
                            float* __restrict__ dst) {
  int g = blockIdx.x * blockDim.x + threadIdx.x;
  if (g >= G4) return;
  int q = g & 3, n = g >> 2;
  const float* s = (q == 0) ? b0 : (q == 1) ? b1 : (q == 2) ? b2 : b3;
  dst[g] = s[n];
}

__device__ __forceinline__ float h2f(unsigned short u) {
  union { unsigned short s; _Float16 h; } c; c.s = u; return (float)c.h;
}
__device__ __forceinline__ unsigned short f2h(float f) {
  union { unsigned short s; _Float16 h; } c; c.h = (_Float16)f; return c.s;
}

// issue 8x16B plain cached loads of x(t) slice, source pre-swizzled so the
// linear LDS write yields LDS[row][c] = x[row][c ^ ((row&7)<<4)]
__device__ __forceinline__ void x_issue(const float* x, int b0, int tid, int t, f32x4* xst) {
  #pragma unroll
  for (int j = 0; j < 8; ++j) {
    const int row  = j * 2 + (tid >> 7);
    const int colb = (tid & 127) * 16;
    const char* src = (const char*)x +
        (((size_t)(b0 + row) * T_SZ + t) * I_SZ) * 4 + (colb ^ ((row & 7) << 4));
    asm volatile("global_load_dwordx4 %0, %1, off" : "=v"(xst[j]) : "v"(src) : "memory");
  }
}
__device__ __forceinline__ void x_write(char* xl, int tid, const f32x4* xst) {
  #pragma unroll
  for (int j = 0; j < 8; ++j)
    *(f32x4*)(xl + j * 4096 + tid * 16) = xst[j];
}

// ---------- persistent recurrence ----------
// 256 blocks x 256 thr, 1/CU. blk = hgrp*4 + bgrp -> chain bgrp pinned to XCD
// pair {bgrp, bgrp+4}. Weights asm-pinned in VGPR/AGPR for all 512 steps.
// h crosses XCDs via LLC (sc0 sc1); x double-buffered in LDS (prefetched one
// step ahead); sync = 64 per-producer flags + one-wave 64-lane poll.
__global__ __launch_bounds__(256, 1) void lstm_recur(
    const float* __restrict__ x,        // [B][T][I] fp32
    const _Float16* __restrict__ Ubt,   // [4096][512]  row 4n+q = U_q[:,n]
    const _Float16* __restrict__ Vt,    // [4096][1024] row 4n+q = V_q[:,n]
    const float* __restrict__ biasw,    // [4096] interleaved
    float* __restrict__ out,            // hidden_seq | h_T | c_T
    _Float16* __restrict__ hbuf,        // [2][64][1024] f16 double buffer
    unsigned* __restrict__ bar)         // flags: chain bgrp at bar + bgrp*256
{
  __shared__ __align__(16) char hsh[32768];    // h slice [16][1024] f16, swizzled
  __shared__ __align__(16) char xlds[65536];   // x dbuf [2][16][512] f32, swizzled

  const int tid  = threadIdx.x;
  const int wv   = tid >> 6;
  const int lane = tid & 63;
  const int lc   = lane & 15;     // col-in-wave / A-row sel
  const int lk   = lane >> 4;     // k-group
  const int q    = lc & 3;        // gate id (0=i,1=f,2=g,3=o)
  const int p    = lc >> 2;       // quad id
  const int blk  = blockIdx.x;
  const int bgrp = blk & 3;       // batch chain (XCD pair)
  const int hgrp = blk >> 2;      // 0..63
  const int col0 = hgrp * 64 + wv * 16;
  const int b0   = bgrp * 16;
  const int sw   = (lc & 7) << 4; // read-side swizzle

  unsigned* flags = bar + bgrp * 256;   // 64 dwords, 1KB-spaced per chain

  // ---- stationary weights: load once, pin via opaque asm ----
  f16x8 bU[16];
  f16x8 bV[32];
  {
    const _Float16* up = Ubt + (size_t)(col0 + lc) * I_SZ + lk * 8;
    #pragma unroll
    for (int ks = 0; ks < 16; ++ks) bU[ks] = *(const f16x8*)(up + ks * 32);
    const _Float16* vp = Vt + (size_t)(col0 + lc) * H_SZ + lk * 8;
    #pragma unroll
    for (int ks = 0; ks < 32; ++ks) bV[ks] = *(const f16x8*)(vp + ks * 32);
  }
  #pragma unroll
  for (int ks = 0; ks < 16; ++ks) asm volatile("" : "+v"(bU[ks]));
  #pragma unroll
  for (int ks = 0; ks < 32; ++ks) asm volatile("" : "+v"(bV[ks]));

  const float bias_v = biasw[col0 + lc];
  const int n_glob = hgrp * 16 + wv * 4 + p;
  const int cb     = hgrp * 16 + wv * 4;
  const size_t HO = (size_t)B_SZ * T_SZ * H_SZ;
  const size_t CO = HO + (size_t)B_SZ * H_SZ;

  float cst[4] = {0.f, 0.f, 0.f, 0.f};

  // ---- prime x(0) into xlds[0] ----
  f32x4 xst[8];
  x_issue(x, b0, tid, 0, xst);
  asm volatile("s_waitcnt vmcnt(0)" ::: "memory");
  __builtin_amdgcn_sched_barrier(0);
  x_write(xlds, tid, xst);
  __syncthreads();

  for (int t = 0; t < T_SZ; ++t) {
    const _Float16* hcur  = hbuf + (size_t)(t & 1) * (B_SZ * H_SZ);
    _Float16*       hnext = hbuf + (size_t)((t + 1) & 1) * (B_SZ * H_SZ);
    char* xl_cur = xlds + (size_t)(t & 1) * 32768;
    char* xl_nxt = xlds + (size_t)((t + 1) & 1) * 32768;

    // ---- B: issue x(t+1) prefetch (in flight across poll) ----
    if (t + 1 < T_SZ) x_issue(x, b0, tid, t + 1, xst);

    f32x4 acc[4];
    acc[0] = f32x4{bias_v, bias_v, bias_v, bias_v};
    acc[1] = f32x4{0.f, 0.f, 0.f, 0.f};
    acc[2] = f32x4{0.f, 0.f, 0.f, 0.f};
    acc[3] = f32x4{0.f, 0.f, 0.f, 0.f};

    // ---- A: x projection from LDS (local; overlaps producer skew) ----
    #pragma unroll
    for (int ks = 0; ks < 16; ++ks) {
      const int cb0 = lk * 32 + ks * 128;
      const f32x4 xa = *(const f32x4*)(xl_cur + (lc << 11) + (cb0 ^ sw));
      const f32x4 xb = *(const f32x4*)(xl_cur + (lc << 11) + ((cb0 + 16) ^ sw));
      f16x8 a = { (_Float16)xa.x, (_Float16)xa.y, (_Float16)xa.z, (_Float16)xa.w,
                  (_Float16)xb.x, (_Float16)xb.y, (_Float16)xb.z, (_Float16)xb.w };
      acc[ks & 3] = __builtin_amdgcn_mfma_f32_16x16x32_f16(a, bU[ks], acc[ks & 3], 0, 0, 0);
    }

    // ---- C: wave0 polls all 64 producer flags in one load/iter ----
    if (t) {
      if (wv == 0) {
        const unsigned* fp = flags + lane;
        unsigned v;
        do {
          asm volatile("global_load_dword %0, %1, off sc0 sc1\n\ts_waitcnt vmcnt(0)"
                       : "=&v"(v) : "v"(fp) : "memory");
        } while (__any(v < (unsigned)t));
      }
      __syncthreads();
      __builtin_amdgcn_sched_barrier(0);
    }

    // ---- D/E/F: h gather (LLC) + drain + stage h and x(t+1) into LDS ----
    {
      const char* src = (const char*)(hcur + (size_t)b0 * H_SZ) + tid * 16;
      f16x8 st0, st1, st2, st3, st4, st5, st6, st7;
      asm volatile("global_load_dwordx4 %0, %1, off sc0 sc1" : "=v"(st0) : "v"(src)          : "memory");
      asm volatile("global_load_dwordx4 %0, %1, off sc0 sc1" : "=v"(st1) : "v"(src + 4096)   : "memory");
      asm volatile("global_load_dwordx4 %0, %1, off sc0 sc1" : "=v"(st2) : "v"(src + 8192)   : "memory");
      asm volatile("global_load_dwordx4 %0, %1, off sc0 sc1" : "=v"(st3) : "v"(src + 12288)  : "memory");
      asm volatile("global_load_dwordx4 %0, %1, off sc0 sc1" : "=v"(st4) : "v"(src + 16384)  : "memory");
      asm volatile("global_load_dwordx4 %0, %1, off sc0 sc1" : "=v"(st5) : "v"(src + 20480)  : "memory");
      asm volatile("global_load_dwordx4 %0, %1, off sc0 sc1" : "=v"(st6) : "v"(src + 24576)  : "memory");
      asm volatile("global_load_dwordx4 %0, %1, off sc0 sc1" : "=v"(st7) : "v"(src + 28672)  : "memory");
      asm volatile("s_waitcnt vmcnt(0)" ::: "memory");   // drains h gather + x prefetch
      __builtin_amdgcn_sched_barrier(0);
      f16x8 st[8] = {st0, st1, st2, st3, st4, st5, st6, st7};
      #pragma unroll
      for (int j = 0; j < 8; ++j) {
        const int byteoff = j * 4096 + tid * 16;
        const int row  = byteoff >> 11;
        const int colb = byteoff & 2047;
        *(f16x8*)(hsh + ((row << 11) | (colb ^ ((row & 7) << 4)))) = st[j];
      }
      if (t + 1 < T_SZ) x_write(xl_nxt, tid, xst);
    }
    __syncthreads();

    // ---- H: h projection from LDS ----
    #pragma unroll
    for (int ks = 0; ks < 32; ++ks) {
      const int a = (lc << 11) | ((lk * 16 + ks * 64) ^ sw);
      const f16x8 hv = *(const f16x8*)(hsh + a);
      acc[ks & 3] = __builtin_amdgcn_mfma_f32_16x16x32_f16(hv, bV[ks], acc[ks & 3], 0, 0, 0);
    }

    // ---- I: gates ----
    float hnf[4];
    #pragma unroll
    for (int r = 0; r < 4; ++r) {
      const float v  = acc[0][r] + acc[1][r] + acc[2][r] + acc[3][r];
      const float sc = (q == 2) ? 2.f : 1.f;
      const float s  = 1.f / (1.f + __expf(-sc * v));
      const float av = (q == 2) ? (2.f * s - 1.f) : s;   // tanh via 2*sigm(2x)-1
      const float x1 = __shfl_xor(av, 1);
      const float x2 = __shfl_xor(av, 2);
      const float x3 = __shfl_xor(av, 3);
      const float gi = (q == 0) ? av : (q == 1) ? x1 : (q == 2) ? x2 : x3;
      const int m1 = q ^ 1;
      const float gf = (m1 == 0) ? av : (m1 == 1) ? x1 : (m1 == 2) ? x2 : x3;
      const int m2 = q ^ 2;
      const float gg = (m2 == 0) ? av : (m2 == 1) ? x1 : (m2 == 2) ? x2 : x3;
      const int m3 = q ^ 3;
      const float go = (m3 == 0) ? av : (m3 == 1) ? x1 : (m3 == 2) ? x2 : x3;
      const float cn = gf * cst[r] + gi * gg;
      const float s2 = 1.f / (1.f + __expf(-2.f * cn));
      hnf[r] = go * (2.f * s2 - 1.f);
      cst[r] = cn;
    }

    // ---- 4x4 shuffle transpose: lane p -> row (b0+lk*4+p), cols cb..cb+3 ----
    const unsigned c01 = (unsigned)f2h(hnf[0]) | ((unsigned)f2h(hnf[1]) << 16);
    const unsigned c23 = (unsigned)f2h(hnf[2]) | ((unsigned)f2h(hnf[3]) << 16);
    const unsigned t01 = __shfl_xor(c01, 4);
    const unsigned t23 = __shfl_xor(c23, 4);
    unsigned r01, r23;
    if (p & 1) { r01 = (t01 >> 16) | (c01 & 0xffff0000u); r23 = (t23 >> 16) | (c23 & 0xffff0000u); }
    else       { r01 = (c01 & 0xffffu) | (t01 << 16);     r23 = (c23 & 0xffffu) | (t23 << 16); }
    const unsigned x01 = __shfl_xor(r01, 8);
    const unsigned x23 = __shfl_xor(r23, 8);
    u32x2 hw;
    if (p < 2) { hw.x = r01; hw.y = x01; }
    else       { hw.x = x23; hw.y = r23; }

    const int row = b0 + lk * 4 + p;

    // ---- J: publish h, then flag; out-store moved off the critical path ----
    if (q == 0 && t < T_SZ - 1) {
      _Float16* hp2 = hnext + (size_t)row * H_SZ + cb;
      asm volatile("global_store_dwordx2 %0, %1, off sc0 sc1" :: "v"(hp2), "v"(hw) : "memory");
    }
    asm volatile("s_waitcnt vmcnt(0)" ::: "memory");
    __syncthreads();
    if (t < T_SZ - 1 && tid == 0) {
      const unsigned* fp = flags + hgrp;
      unsigned tv = (unsigned)(t + 1);
      asm volatile("global_store_dword %0, %1, off sc0 sc1" :: "v"(fp), "v"(tv) : "memory");
    }

    // ---- K: hidden_seq store (drains under next step's vmcnt) ----
    if (q == 0) {
      f32x4 of = { h2f((unsigned short)(hw.x & 0xffffu)), h2f((unsigned short)(hw.x >> 16)),
                   h2f((unsigned short)(hw.y & 0xffffu)), h2f((unsigned short)(hw.y >> 16)) };
      *(f32x4*)(out + (size_t)row * (T_SZ * H_SZ) + (size_t)t * H_SZ + cb) = of;
      if (t == T_SZ - 1) {
        #pragma unroll
        for (int r = 0; r < 4; ++r) {
          const int b = b0 + lk * 4 + r;
          out[HO + (size_t)b * H_SZ + n_glob] = hnf[r];
          out[CO + (size_t)b * H_SZ + n_glob] = cst[r];
        }
      }
    }
  }
}

extern "C" void kernel_launch(void* const* d_in, const int* in_sizes, int n_in,
                              void* d_out, int out_size, void* d_ws, size_t ws_size,
                              hipStream_t stream) {
  const float* x = (const float*)d_in[0];
  const float* U[4]  = {(const float*)d_in[1], (const float*)d_in[4],
                        (const float*)d_in[7], (const float*)d_in[10]};
  const float* V[4]  = {(const float*)d_in[2], (const float*)d_in[5],
                        (const float*)d_in[8], (const float*)d_in[11]};
  const float* bb[4] = {(const float*)d_in[3], (const float*)d_in[6],
                        (const float*)d_in[9], (const float*)d_in[12]};
  float* out = (float*)d_out;

  char* p = (char*)d_ws;
  _Float16* Ubt = (_Float16*)p; p += (size_t)G4 * I_SZ * 2;          // 4 MB
  _Float16* Vt  = (_Float16*)p; p += (size_t)G4 * H_SZ * 2;          // 8 MB
  float*    biasw = (float*)p;  p += (size_t)G4 * 4;                 // 16 KB
  _Float16* hbuf  = (_Float16*)p; p += (size_t)2 * B_SZ * H_SZ * 2;  // 256 KB
  unsigned* bar   = (unsigned*)p;                                    // 16 KB

  for (int qq = 0; qq < 4; ++qq)
    hipLaunchKernelGGL(trans_kernel, dim3(16, 8), dim3(256), 0, stream, U[qq], Ubt, I_SZ, qq);
  for (int qq = 0; qq < 4; ++qq)
    hipLaunchKernelGGL(trans_kernel, dim3(16, 16), dim3(256), 0, stream, V[qq], Vt, H_SZ, qq);
  hipLaunchKernelGGL(bias_kernel, dim3(16), dim3(256), 0, stream, bb[0], bb[1], bb[2], bb[3], biasw);

  // h(0) = 0 (buffer 0 read at t=0); flags = 0 (graph-replay safe)
  hipMemsetAsync(hbuf, 0, (size_t)B_SZ * H_SZ * 2, stream);
  hipMemsetAsync(bar, 0, 16384, stream);

  hipLaunchKernelGGL(lstm_recur, dim3(NBLK), dim3(256), 0, stream,
                     x, Ubt, Vt, biasw, out, hbuf, bar);
}